// Round 11
// baseline (235.329 us; speedup 1.0000x reference)
//
#include <hip/hip_runtime.h>
#include <hip/hip_bf16.h>

#define N_NODES 50000
#define N_EDGES 500000
#define MUL0 16
#define MUL1 8
#define DIM 40            // MUL0 + 3*MUL1
#define N_BASIS 10
#define MID 32
#define WNUM 576          // 256 + 128 + 128 + 64
#define SCAN_BLOCKS 196   // ceil(50000/256)
#define N_GROUPS (N_EDGES / 16)   // 31250 exact

typedef __attribute__((ext_vector_type(8))) short bf16x8_t;
typedef __attribute__((ext_vector_type(4))) float f32x4_t;

__device__ __forceinline__ float bf2f(unsigned short u) {
  return __uint_as_float(((unsigned int)u) << 16);
}
__device__ __forceinline__ unsigned short f2bf(float f) {
  unsigned int x = __float_as_uint(f);
  unsigned int r = x + 0x7fffu + ((x >> 16) & 1u);  // RNE
  return (unsigned short)(r >> 16);
}
// packed f32x2 -> bf16x2 (v_cvt_pk_bf16_f32; RNE)
__device__ __forceinline__ unsigned pk2bf(float a, float b) {
  float2 f; f.x = a; f.y = b;
  __hip_bfloat162 h = __float22bfloat162_rn(f);
  return *reinterpret_cast<unsigned*>(&h);
}
// gamma is all-ones: bf16-packed pair -> 0x3F803F80 ; f32 -> 0x3F800000.
// Measured (r4/r5): live inputs are f32; bf16 branch kept as insurance.
__device__ __forceinline__ bool detect_bf16(const void* gamma) {
  return ((const unsigned int*)gamma)[0] == 0x3F803F80u;
}
template <bool BF16>
__device__ __forceinline__ float ld(const void* p, size_t i) {
  if (BF16) return bf2f(((const unsigned short*)p)[i]);
  return ((const float*)p)[i];
}

#define C_INV_SQRT10 0.31622776601683794f
#define C_INV_SQRT32 0.17677669529663687f
#define C_INV_SQRT3  0.5773502691896258f
#define C_A0C        0.20412414523193154f   // sqrt(1/24) == A0 == A1*INV_SQRT3

__device__ __forceinline__ f32x4_t mfma16x16x32(bf16x8_t a, bf16x8_t b, f32x4_t c) {
  return __builtin_amdgcn_mfma_f32_16x16x32_bf16(a, b, c, 0, 0, 0);
}

// ---------------- CSR build: ONE atomic pass, no scanC ----------------
__global__ __launch_bounds__(256) void rank_kernel(
    const int* __restrict__ edge_dst, int* __restrict__ cnt,
    int* __restrict__ rank) {
  int e = blockIdx.x * 256 + threadIdx.x;
  if (e < N_EDGES) rank[e] = atomicAdd(&cnt[edge_dst[e]], 1);
}

__global__ __launch_bounds__(256) void scanA_kernel(
    const int* __restrict__ cnt, int* __restrict__ off, int* __restrict__ btot) {
  __shared__ int s[256];
  const int tid = threadIdx.x;
  const int i = blockIdx.x * 256 + tid;
  int v = (i < N_NODES) ? cnt[i] : 0;
  s[tid] = v;
  __syncthreads();
  for (int d = 1; d < 256; d <<= 1) {
    int t = (tid >= d) ? s[tid - d] : 0;
    __syncthreads();
    s[tid] += t;
    __syncthreads();
  }
  if (i < N_NODES) off[i] = s[tid] - v;            // block-local exclusive
  if (tid == 255) btot[blockIdx.x] = s[255];
}

__global__ __launch_bounds__(256) void scanB_kernel(
    const int* __restrict__ btot, int* __restrict__ bbase) {
  __shared__ int s[256];
  const int tid = threadIdx.x;
  int v = (tid < SCAN_BLOCKS) ? btot[tid] : 0;
  s[tid] = v;
  __syncthreads();
  for (int d = 1; d < 256; d <<= 1) {
    int t = (tid >= d) ? s[tid - d] : 0;
    __syncthreads();
    s[tid] += t;
    __syncthreads();
  }
  if (tid < SCAN_BLOCKS) bbase[tid] = s[tid] - v;  // exclusive block base
}

// epos[e] = off[dst] + bbase[dst>>8] + rank[e]  (off stays partial; no scanC)
__global__ __launch_bounds__(256) void posc_kernel(
    const int* __restrict__ edge_dst, const int* __restrict__ rank,
    const int* __restrict__ off, const int* __restrict__ bbase,
    int* __restrict__ epos) {
  int e = blockIdx.x * 256 + threadIdx.x;
  if (e >= N_EDGES) return;
  int d = edge_dst[e];
  epos[e] = off[d] + bbase[d >> 8] + rank[e];
}

// ---------------- phase 1: MFMA edge kernel (512-thread blocks, 2 blk/CU = 16 waves/CU) ----------------
// r9 lesson: no B-frag reg-cache (spills). All B-frags from LDS broadcast.
// Per-wave staging S (floats, 832/wave):
//   +0   shs [4 comp][16 edge]
//   +64  sss [16 u][16 edge]
//   +320 vds [8 u][16 edge]
//   +448 vst [24 cc=u*3+i][16 edge]
//   evs overlays +64.. : [16 edge][42] (sss/vds/vst dead after MFMA loops)

template <bool BF16>
__device__ void edge_mfma_body(
    const void* __restrict__ x,
    const void* __restrict__ edge_sh,
    const void* __restrict__ elemb,
    const void* __restrict__ W1,
    const void* __restrict__ W2,
    const int* __restrict__ edge_src,
    const int* __restrict__ epos,
    unsigned short* __restrict__ ev,
    short* __restrict__ w2b, float* __restrict__ w1s, float* __restrict__ stg)
{
  const int tid = threadIdx.x;

  // stage W2 into B-frag order: w2b[t*512+q*128+n*8+j] = bf16(W2[q*8+j][16t+n])
  for (int i = tid; i < 36 * 512; i += 512) {
    int m = i / WNUM;            // = q*8+j
    int col = i - m * WNUM;      // = t*16+n
    int q = m >> 3, j = m & 7;
    int t = col >> 4, n = col & 15;
    short val;
    if (BF16) val = (short)((const unsigned short*)W2)[i];
    else      val = (short)f2bf(((const float*)W2)[i]);
    w2b[t * 512 + q * 128 + n * 8 + j] = val;
  }
  for (int i = tid; i < N_BASIS * MID; i += 512) w1s[i] = ld<BF16>(W1, i);
  __syncthreads();

  const int lane = tid & 63;
  const int wid  = tid >> 6;         // 0..7
  const int quad = lane >> 4;
  const int l16  = lane & 15;
  float* S = stg + wid * 832;

  for (int gi = blockIdx.x * 8 + wid; gi < N_GROUPS; gi += gridDim.x * 8) {
    const int e0 = gi * 16;
    __builtin_amdgcn_wave_barrier();  // prev-iter evs reads vs this-iter staging writes

    // CSR slot for the scattered store (coalesced epos read)
    const int posA = epos[e0 + (lane >> 2)];
    const int posB = (lane < 16) ? epos[e0 + lane] : 0;

    // ---- stage edge_sh ----
    if (lane < 16) {
      if (BF16) {
        uint2 sw = *reinterpret_cast<const uint2*>(
            (const unsigned short*)edge_sh + (size_t)(e0 + lane) * 4);
        S[0 * 16 + lane] = __uint_as_float(sw.x << 16);
        S[1 * 16 + lane] = __uint_as_float(sw.x & 0xffff0000u);
        S[2 * 16 + lane] = __uint_as_float(sw.y << 16);
        S[3 * 16 + lane] = __uint_as_float(sw.y & 0xffff0000u);
      } else {
        float4 s4 = *reinterpret_cast<const float4*>(
            (const float*)edge_sh + (size_t)(e0 + lane) * 4);
        S[0 * 16 + lane] = s4.x; S[1 * 16 + lane] = s4.y;
        S[2 * 16 + lane] = s4.z; S[3 * 16 + lane] = s4.w;
      }
    }

    // ---- stage x[src]: col<16 -> sss, col>=16 -> vst ----
    {
      const int src = edge_src[e0 + l16];
      if (BF16) {
        const uint4* xr = reinterpret_cast<const uint4*>(
            (const unsigned short*)x + (size_t)src * DIM);
        uint4 c = xr[quad];
        unsigned wv[4] = {c.x, c.y, c.z, c.w};
        #pragma unroll
        for (int p = 0; p < 4; ++p) {
          int col = quad * 8 + 2 * p;
          float lo = __uint_as_float(wv[p] << 16);
          float hi = __uint_as_float(wv[p] & 0xffff0000u);
          int off0 = (col < 16) ? (64 + col * 16) : (448 + (col - 16) * 16);
          int off1 = (col + 1 < 16) ? (64 + (col + 1) * 16) : (448 + (col - 15) * 16);
          S[off0 + l16] = lo;
          S[off1 + l16] = hi;
        }
        if (lane < 16) {
          uint4 c4 = xr[4];
          unsigned wv4[4] = {c4.x, c4.y, c4.z, c4.w};
          #pragma unroll
          for (int p = 0; p < 4; ++p) {
            int col = 32 + 2 * p;
            S[448 + (col - 16) * 16 + lane] = __uint_as_float(wv4[p] << 16);
            S[448 + (col - 15) * 16 + lane] = __uint_as_float(wv4[p] & 0xffff0000u);
          }
        }
      } else {
        const float4* xr = reinterpret_cast<const float4*>(
            (const float*)x + (size_t)src * DIM);
        #pragma unroll
        for (int cc = 0; cc < 2; ++cc) {
          int c = quad + cc * 4;
          float4 t = xr[c];
          float vv[4] = {t.x, t.y, t.z, t.w};
          #pragma unroll
          for (int p = 0; p < 4; ++p) {
            int col = 4 * c + p;
            int offp = (col < 16) ? (64 + col * 16) : (448 + (col - 16) * 16);
            S[offp + l16] = vv[p];
          }
        }
        if (quad < 2) {
          int c = 8 + quad;
          float4 t = xr[c];
          float vv[4] = {t.x, t.y, t.z, t.w};
          #pragma unroll
          for (int p = 0; p < 4; ++p) {
            int col = 4 * c + p;
            S[448 + (col - 16) * 16 + l16] = vv[p];
          }
        }
      }
    }
    __builtin_amdgcn_wave_barrier();

    // ---- vds = (v . sh1) * inv_sqrt3 ----
    #pragma unroll
    for (int p = 0; p < 2; ++p) {
      int idx = lane + p * 64;
      int u = idx >> 4, e = idx & 15;
      float vdv = (S[448 + (u * 3 + 0) * 16 + e] * S[16 + e] +
                   S[448 + (u * 3 + 1) * 16 + e] * S[32 + e] +
                   S[448 + (u * 3 + 2) * 16 + e] * S[48 + e]) * C_INV_SQRT3;
      S[320 + u * 16 + e] = vdv;
    }
    __builtin_amdgcn_wave_barrier();

    // ---- h A-frag: lane holds h[edge=l16][k=quad*8+j] ----
    bf16x8_t af;
    {
      float eb[N_BASIS];
      if (BF16) {
        const unsigned short* er = (const unsigned short*)elemb + (size_t)(e0 + l16) * N_BASIS;
        #pragma unroll
        for (int p = 0; p < 5; ++p) {
          unsigned uv = *reinterpret_cast<const unsigned*>(er + p * 2);
          eb[2 * p]     = __uint_as_float(uv << 16);
          eb[2 * p + 1] = __uint_as_float(uv & 0xffff0000u);
        }
      } else {
        const float* er = (const float*)elemb + (size_t)(e0 + l16) * N_BASIS;
        #pragma unroll
        for (int p = 0; p < 5; ++p) {
          float2 fv = *reinterpret_cast<const float2*>(er + p * 2);
          eb[2 * p] = fv.x; eb[2 * p + 1] = fv.y;
        }
      }
      float hv[8];
      #pragma unroll
      for (int j = 0; j < 8; ++j) {
        int k = quad * 8 + j;
        float p = 0.f;
        #pragma unroll
        for (int b = 0; b < N_BASIS; ++b) p += eb[b] * w1s[b * MID + k];
        float z = p * C_INV_SQRT10;
        hv[j] = z / (1.f + __expf(-z)) * C_INV_SQRT32;
      }
      __align__(16) unsigned au[4];
      #pragma unroll
      for (int j = 0; j < 4; ++j) au[j] = pk2bf(hv[2 * j], hv[2 * j + 1]);
      af = *reinterpret_cast<const bf16x8_t*>(au);
    }

    f32x4_t s0 = *reinterpret_cast<const f32x4_t*>(&S[quad * 4]);  // sh0, 4 edges

    f32x4_t out0 = {0.f, 0.f, 0.f, 0.f};
    f32x4_t tsv  = {0.f, 0.f, 0.f, 0.f};
    f32x4_t tv0  = {0.f, 0.f, 0.f, 0.f};
    f32x4_t tv1  = {0.f, 0.f, 0.f, 0.f};
    f32x4_t tv2  = {0.f, 0.f, 0.f, 0.f};
    const f32x4_t zero = {0.f, 0.f, 0.f, 0.f};
    const int usel = (l16 >> 3);

    #pragma unroll
    for (int t = 0; t < 16; ++t) {   // ss0: u=t, k=l16 (B-frag from LDS broadcast)
      bf16x8_t bf = *reinterpret_cast<const bf16x8_t*>(&w2b[t * 512 + lane * 8]);
      f32x4_t D = mfma16x16x32(af, bf, zero);
      f32x4_t sv = *reinterpret_cast<const f32x4_t*>(&S[64 + t * 16 + quad * 4]);
      out0 += D * (sv * s0);
    }
    #pragma unroll
    for (int t = 0; t < 8; ++t) {    // vv0
      bf16x8_t bf = *reinterpret_cast<const bf16x8_t*>(&w2b[(16 + t) * 512 + lane * 8]);
      f32x4_t D = mfma16x16x32(af, bf, zero);
      f32x4_t vdv = *reinterpret_cast<const f32x4_t*>(&S[320 + t * 16 + quad * 4]);
      out0 += D * vdv;
    }
    #pragma unroll
    for (int t = 0; t < 8; ++t) {    // sv1: u=2t+usel, k=l16&7
      bf16x8_t bf = *reinterpret_cast<const bf16x8_t*>(&w2b[(24 + t) * 512 + lane * 8]);
      f32x4_t D = mfma16x16x32(af, bf, zero);
      int u = 2 * t + usel;
      f32x4_t sv = *reinterpret_cast<const f32x4_t*>(&S[64 + u * 16 + quad * 4]);
      tsv += D * sv;
    }
    #pragma unroll
    for (int t = 0; t < 4; ++t) {    // vs1: u=2t+usel, k=l16&7
      bf16x8_t bf = *reinterpret_cast<const bf16x8_t*>(&w2b[(32 + t) * 512 + lane * 8]);
      f32x4_t D = mfma16x16x32(af, bf, zero);
      int u = 2 * t + usel;
      f32x4_t v0 = *reinterpret_cast<const f32x4_t*>(&S[448 + (u * 3 + 0) * 16 + quad * 4]);
      f32x4_t v1 = *reinterpret_cast<const f32x4_t*>(&S[448 + (u * 3 + 1) * 16 + quad * 4]);
      f32x4_t v2 = *reinterpret_cast<const f32x4_t*>(&S[448 + (u * 3 + 2) * 16 + quad * 4]);
      tv0 += D * v0; tv1 += D * v1; tv2 += D * v2;
    }

    // combine u-parity halves (lanes l16 and l16^8)
    #pragma unroll
    for (int r = 0; r < 4; ++r) {
      tsv[r] += __shfl_xor(tsv[r], 8, 64);
      tv0[r] += __shfl_xor(tv0[r], 8, 64);
      tv1[r] += __shfl_xor(tv1[r], 8, 64);
      tv2[r] += __shfl_xor(tv2[r], 8, 64);
    }
    __builtin_amdgcn_wave_barrier();  // MFMA-loop S reads done; evs overlay begins

    // ---- epilogue into evs overlay (base +64, stride 42) ----
    #pragma unroll
    for (int r = 0; r < 4; ++r)
      S[64 + (quad * 4 + r) * 42 + l16] = C_A0C * out0[r];
    if (l16 < 8) {
      f32x4_t h1x = *reinterpret_cast<const f32x4_t*>(&S[16 + quad * 4]);
      f32x4_t h1y = *reinterpret_cast<const f32x4_t*>(&S[32 + quad * 4]);
      f32x4_t h1z = *reinterpret_cast<const f32x4_t*>(&S[48 + quad * 4]);
      #pragma unroll
      for (int r = 0; r < 4; ++r) {
        int rowb = 64 + (quad * 4 + r) * 42 + 16 + 3 * l16;
        S[rowb + 0] = C_A0C * (tsv[r] * h1x[r] + tv0[r] * s0[r]);
        S[rowb + 1] = C_A0C * (tsv[r] * h1y[r] + tv1[r] * s0[r]);
        S[rowb + 2] = C_A0C * (tsv[r] * h1z[r] + tv2[r] * s0[r]);
      }
    }
    __builtin_amdgcn_wave_barrier();

    // ---- scattered CSR-slot store: edge row -> ev[pos] (80B, 5x uint4) ----
    {
      const int edge = lane >> 2, chunk = lane & 3;     // chunks 0..3
      const float* rp = &S[64 + edge * 42 + chunk * 8];
      uint4 t;
      t.x = pk2bf(rp[0], rp[1]); t.y = pk2bf(rp[2], rp[3]);
      t.z = pk2bf(rp[4], rp[5]); t.w = pk2bf(rp[6], rp[7]);
      *reinterpret_cast<uint4*>(ev + (size_t)posA * DIM + chunk * 8) = t;
      if (lane < 16) {                                   // chunk 4 (cols 32..39)
        const float* rq = &S[64 + lane * 42 + 32];
        uint4 t2;
        t2.x = pk2bf(rq[0], rq[1]); t2.y = pk2bf(rq[2], rq[3]);
        t2.z = pk2bf(rq[4], rq[5]); t2.w = pk2bf(rq[6], rq[7]);
        *reinterpret_cast<uint4*>(ev + (size_t)posB * DIM + 32) = t2;
      }
    }
  }
}

__global__ __launch_bounds__(512, 4) void edge_mfma_kernel(
    const void* __restrict__ x,
    const void* __restrict__ edge_sh,
    const void* __restrict__ elemb,
    const void* __restrict__ W1,
    const void* __restrict__ W2,
    const void* __restrict__ gamma,    // dtype probe (all ones)
    const int* __restrict__ edge_src,
    const int* __restrict__ epos,
    unsigned short* __restrict__ ev)
{
  __shared__ __align__(16) short w2b[36 * 512];   // 36,864 B
  __shared__ __align__(16) float w1s[N_BASIS * MID];
  __shared__ __align__(16) float stg[8 * 832];    // 26,624 B -> 64,768 B total, 2 blk/CU, 16 waves/CU

  if (detect_bf16(gamma))
    edge_mfma_body<true >(x, edge_sh, elemb, W1, W2, edge_src, epos, ev, w2b, w1s, stg);
  else
    edge_mfma_body<false>(x, edge_sh, elemb, W1, W2, edge_src, epos, ev, w2b, w1s, stg);
}

// ---------------- phase 2: contiguous gather + LayerNorm (2 lanes/node) ----------------

template <bool BF16>
__device__ __forceinline__ void node_body(
    const unsigned short* __restrict__ ev,   // CSR-ordered rows
    const int* __restrict__ cnt,
    const int* __restrict__ off,             // block-partial offsets
    const int* __restrict__ bbase,           // scan block bases
    const void* __restrict__ gamma,
    const void* __restrict__ beta,
    const int* __restrict__ avg,
    void* __restrict__ out, int n, int half)
{
  const int c = cnt[n];
  const int o = off[n] + bbase[n >> 8];
  float s[20];
  #pragma unroll
  for (int d = 0; d < 20; ++d) s[d] = 0.f;

  // this half's 20 bf16 = 5 uint2 per row; row stride = 10 uint2
  const uint2* p = reinterpret_cast<const uint2*>(ev) + (size_t)o * 10 + half * 5;
  for (int j = 0; j < c; ++j) {
    #pragma unroll
    for (int q = 0; q < 5; ++q) {
      uint2 w = p[(size_t)j * 10 + q];
      s[q * 4 + 0] += __uint_as_float(w.x << 16);
      s[q * 4 + 1] += __uint_as_float(w.x & 0xffff0000u);
      s[q * 4 + 2] += __uint_as_float(w.y << 16);
      s[q * 4 + 3] += __uint_as_float(w.y & 0xffff0000u);
    }
  }

  const float inv = rsqrtf((float)avg[0]);
  float psum = 0.f;
  #pragma unroll
  for (int d = 0; d < 20; ++d) { s[d] *= inv; psum += s[d]; }
  const float mean = (psum + __shfl_xor(psum, 1, 64)) * (1.f / DIM);
  float pvar = 0.f;
  #pragma unroll
  for (int d = 0; d < 20; ++d) { float dd = s[d] - mean; pvar += dd * dd; }
  const float var = (pvar + __shfl_xor(pvar, 1, 64)) * (1.f / DIM);
  const float r = rsqrtf(var + 1e-5f);

  const int gb = half * 20;
  if (BF16) {
    #pragma unroll
    for (int d = 0; d < 20; ++d) {
      float y = (s[d] - mean) * r * ld<true>(gamma, gb + d) + ld<true>(beta, gb + d);
      ((unsigned short*)out)[(size_t)n * DIM + gb + d] = f2bf(y);
    }
  } else {
    float4* op = reinterpret_cast<float4*>((float*)out + (size_t)n * DIM + gb);
    #pragma unroll
    for (int q = 0; q < 5; ++q) {
      float4 t;
      t.x = (s[q*4+0] - mean) * r * ld<false>(gamma, gb+q*4+0) + ld<false>(beta, gb+q*4+0);
      t.y = (s[q*4+1] - mean) * r * ld<false>(gamma, gb+q*4+1) + ld<false>(beta, gb+q*4+1);
      t.z = (s[q*4+2] - mean) * r * ld<false>(gamma, gb+q*4+2) + ld<false>(beta, gb+q*4+2);
      t.w = (s[q*4+3] - mean) * r * ld<false>(gamma, gb+q*4+3) + ld<false>(beta, gb+q*4+3);
      op[q] = t;
    }
  }
}

__global__ __launch_bounds__(256) void node_kernel(
    const unsigned short* __restrict__ ev,
    const int* __restrict__ cnt,
    const int* __restrict__ off,
    const int* __restrict__ bbase,
    const void* __restrict__ gamma,
    const void* __restrict__ beta,
    const int* __restrict__ avg,
    void* __restrict__ out)
{
  const int t = blockIdx.x * blockDim.x + threadIdx.x;
  const int n = t >> 1;
  if (n >= N_NODES) return;
  const int half = t & 1;
  if (detect_bf16(gamma)) node_body<true >(ev, cnt, off, bbase, gamma, beta, avg, out, n, half);
  else                    node_body<false>(ev, cnt, off, bbase, gamma, beta, avg, out, n, half);
}

extern "C" void kernel_launch(void* const* d_in, const int* in_sizes, int n_in,
                              void* d_out, int out_size, void* d_ws, size_t ws_size,
                              hipStream_t stream) {
  const void* x       = d_in[0];
  const void* edge_sh = d_in[1];
  const void* elemb   = d_in[2];
  const void* W1      = d_in[3];
  const void* W2      = d_in[4];
  const void* gamma   = d_in[5];
  const void* beta    = d_in[6];
  const int* edge_src = (const int*)d_in[7];
  const int* edge_dst = (const int*)d_in[8];
  const int* avg      = (const int*)d_in[9];

  // workspace layout (44.4 MB)
  char* wsb = (char*)d_ws;
  unsigned short* ev = (unsigned short*)(wsb);            // 40,000,000 B (CSR order)
  int* epos  = (int*)(wsb + 40000000);                    //  2,000,000 B
  int* rank  = (int*)(wsb + 42000000);                    //  2,000,000 B
  int* cnt   = (int*)(wsb + 44000000);                    //    200,000 B
  int* off   = (int*)(wsb + 44200000);                    //    200,000 B
  int* btot  = (int*)(wsb + 44400000);                    //        784 B
  int* bbase = (int*)(wsb + 44400800);                    //        784 B

  hipMemsetAsync(cnt, 0, 200000, stream);  // zero counts only

  const int EB = (N_EDGES + 255) / 256;    // 1954
  rank_kernel <<<EB, 256, 0, stream>>>(edge_dst, cnt, rank);
  scanA_kernel<<<SCAN_BLOCKS, 256, 0, stream>>>(cnt, off, btot);
  scanB_kernel<<<1, 256, 0, stream>>>(btot, bbase);
  posc_kernel <<<EB, 256, 0, stream>>>(edge_dst, rank, off, bbase, epos);

  edge_mfma_kernel<<<512, 512, 0, stream>>>(x, edge_sh, elemb, W1, W2, gamma,
                                            edge_src, epos, ev);

  const int NB2 = (2 * N_NODES + 255) / 256;  // 391
  node_kernel<<<NB2, 256, 0, stream>>>(ev, cnt, off, bbase,
                                       gamma, beta, avg, d_out);
}

// Round 12
// 232.607 us; speedup vs baseline: 1.0117x; 1.0117x over previous
//
#include <hip/hip_runtime.h>
#include <hip/hip_bf16.h>

#define N_NODES 50000
#define N_EDGES 500000
#define MUL0 16
#define MUL1 8
#define DIM 40            // MUL0 + 3*MUL1
#define N_BASIS 10
#define MID 32
#define WNUM 576          // 256 + 128 + 128 + 64
#define SCAN_BLOCKS 196   // ceil(50000/256)
#define N_GROUPS (N_EDGES / 16)   // 31250 exact

typedef __attribute__((ext_vector_type(8))) short bf16x8_t;
typedef __attribute__((ext_vector_type(4))) float f32x4_t;

__device__ __forceinline__ float bf2f(unsigned short u) {
  return __uint_as_float(((unsigned int)u) << 16);
}
__device__ __forceinline__ unsigned short f2bf(float f) {
  unsigned int x = __float_as_uint(f);
  unsigned int r = x + 0x7fffu + ((x >> 16) & 1u);  // RNE
  return (unsigned short)(r >> 16);
}
// packed f32x2 -> bf16x2 (v_cvt_pk_bf16_f32; RNE)
__device__ __forceinline__ unsigned pk2bf(float a, float b) {
  float2 f; f.x = a; f.y = b;
  __hip_bfloat162 h = __float22bfloat162_rn(f);
  return *reinterpret_cast<unsigned*>(&h);
}
// gamma is all-ones: bf16-packed pair -> 0x3F803F80 ; f32 -> 0x3F800000.
// Measured (r4/r5): live inputs are f32; bf16 branch kept as insurance.
__device__ __forceinline__ bool detect_bf16(const void* gamma) {
  return ((const unsigned int*)gamma)[0] == 0x3F803F80u;
}
template <bool BF16>
__device__ __forceinline__ float ld(const void* p, size_t i) {
  if (BF16) return bf2f(((const unsigned short*)p)[i]);
  return ((const float*)p)[i];
}

#define C_INV_SQRT10 0.31622776601683794f
#define C_INV_SQRT32 0.17677669529663687f
#define C_INV_SQRT3  0.5773502691896258f
#define C_A0C        0.20412414523193154f   // sqrt(1/24) == A0 == A1*INV_SQRT3

__device__ __forceinline__ f32x4_t mfma16x16x32(bf16x8_t a, bf16x8_t b, f32x4_t c) {
  return __builtin_amdgcn_mfma_f32_16x16x32_bf16(a, b, c, 0, 0, 0);
}

// ---------------- CSR build: ONE atomic pass + ONE merged scan ----------------
__global__ __launch_bounds__(256) void rank_kernel(
    const int* __restrict__ edge_dst, int* __restrict__ cnt,
    int* __restrict__ rank) {
  int e = blockIdx.x * 256 + threadIdx.x;
  if (e < N_EDGES) rank[e] = atomicAdd(&cnt[edge_dst[e]], 1);
}

// scanA (block-local exclusive scan of cnt) + scanB (scan of block totals)
// merged via last-block-done pattern. G16-safe: producers __threadfence()
// before the device-scope counter add; the last block re-reads btot with
// atomicAdd(p,0) RMWs (device-coherent path, no stale L1).
__global__ __launch_bounds__(256) void scanAB_kernel(
    const int* __restrict__ cnt, int* __restrict__ off, int* __restrict__ btot,
    int* __restrict__ bbase, int* __restrict__ done) {
  __shared__ int s[256];
  __shared__ int isLast;
  const int tid = threadIdx.x;
  const int i = blockIdx.x * 256 + tid;
  int v = (i < N_NODES) ? cnt[i] : 0;
  s[tid] = v;
  __syncthreads();
  for (int d = 1; d < 256; d <<= 1) {
    int t = (tid >= d) ? s[tid - d] : 0;
    __syncthreads();
    s[tid] += t;
    __syncthreads();
  }
  if (i < N_NODES) off[i] = s[tid] - v;            // block-local exclusive
  if (tid == 255) btot[blockIdx.x] = s[255];

  __threadfence();                                 // publish btot
  if (tid == 0) isLast = (atomicAdd(done, 1) == SCAN_BLOCKS - 1);
  __syncthreads();
  if (!isLast) return;

  // last block: exclusive scan of btot -> bbase
  __threadfence();
  int bv = (tid < SCAN_BLOCKS) ? atomicAdd(&btot[tid], 0) : 0;  // coherent read
  s[tid] = bv;
  __syncthreads();
  for (int d = 1; d < 256; d <<= 1) {
    int t = (tid >= d) ? s[tid - d] : 0;
    __syncthreads();
    s[tid] += t;
    __syncthreads();
  }
  if (tid < SCAN_BLOCKS) bbase[tid] = s[tid] - bv;
}

// ---------------- phase 1: MFMA edge kernel (r10 core; pos fused in) ----------------
// r9 lesson: no B-frag reg-cache (spills at (256,3) budget).
// r11 lesson: 512-thr/(512,4) forces 64-VGPR step -> spills. Stay at 256/(256,3).
// Per-wave staging S (floats, 832/wave):
//   +0   shs [4 comp][16 edge]
//   +64  sss [16 u][16 edge]
//   +320 vds [8 u][16 edge]
//   +448 vst [24 cc=u*3+i][16 edge]
//   evs overlays +64.. : [16 edge][42] (sss/vds/vst dead after MFMA loops)

template <bool BF16>
__device__ void edge_mfma_body(
    const void* __restrict__ x,
    const void* __restrict__ edge_sh,
    const void* __restrict__ elemb,
    const void* __restrict__ W1,
    const void* __restrict__ W2,
    const int* __restrict__ edge_src,
    const int* __restrict__ edge_dst,
    const int* __restrict__ rank,
    const int* __restrict__ off,
    const int* __restrict__ bbase,
    unsigned short* __restrict__ ev,
    short* __restrict__ w2b, float* __restrict__ w1s, float* __restrict__ stg)
{
  const int tid = threadIdx.x;

  // stage W2 into B-frag order: w2b[t*512+q*128+n*8+j] = bf16(W2[q*8+j][16t+n])
  for (int i = tid; i < 36 * 512; i += 256) {
    int m = i / WNUM;            // = q*8+j
    int col = i - m * WNUM;      // = t*16+n
    int q = m >> 3, j = m & 7;
    int t = col >> 4, n = col & 15;
    short val;
    if (BF16) val = (short)((const unsigned short*)W2)[i];
    else      val = (short)f2bf(((const float*)W2)[i]);
    w2b[t * 512 + q * 128 + n * 8 + j] = val;
  }
  for (int i = tid; i < N_BASIS * MID; i += 256) w1s[i] = ld<BF16>(W1, i);
  __syncthreads();

  const int lane = tid & 63;
  const int wid  = tid >> 6;
  const int quad = lane >> 4;
  const int l16  = lane & 15;
  float* S = stg + wid * 832;

  for (int gi = blockIdx.x * 4 + wid; gi < N_GROUPS; gi += gridDim.x * 4) {
    const int e0 = gi * 16;
    __builtin_amdgcn_wave_barrier();  // prev-iter evs reads vs this-iter staging writes

    // CSR slot computed in-kernel (posc fused): lane l holds pos of edge e0+l16
    const int eL   = e0 + l16;
    const int dL   = edge_dst[eL];
    const int posv = off[dL] + bbase[dL >> 8] + rank[eL];
    const int posA = __shfl(posv, lane >> 2, 64);   // edge lane>>2 (0..15)
    const int posB = posv;                           // used by lanes < 16

    // ---- stage edge_sh ----
    if (lane < 16) {
      if (BF16) {
        uint2 sw = *reinterpret_cast<const uint2*>(
            (const unsigned short*)edge_sh + (size_t)(e0 + lane) * 4);
        S[0 * 16 + lane] = __uint_as_float(sw.x << 16);
        S[1 * 16 + lane] = __uint_as_float(sw.x & 0xffff0000u);
        S[2 * 16 + lane] = __uint_as_float(sw.y << 16);
        S[3 * 16 + lane] = __uint_as_float(sw.y & 0xffff0000u);
      } else {
        float4 s4 = *reinterpret_cast<const float4*>(
            (const float*)edge_sh + (size_t)(e0 + lane) * 4);
        S[0 * 16 + lane] = s4.x; S[1 * 16 + lane] = s4.y;
        S[2 * 16 + lane] = s4.z; S[3 * 16 + lane] = s4.w;
      }
    }

    // ---- stage x[src]: col<16 -> sss, col>=16 -> vst ----
    {
      const int src = edge_src[e0 + l16];
      if (BF16) {
        const uint4* xr = reinterpret_cast<const uint4*>(
            (const unsigned short*)x + (size_t)src * DIM);
        uint4 c = xr[quad];
        unsigned wv[4] = {c.x, c.y, c.z, c.w};
        #pragma unroll
        for (int p = 0; p < 4; ++p) {
          int col = quad * 8 + 2 * p;
          float lo = __uint_as_float(wv[p] << 16);
          float hi = __uint_as_float(wv[p] & 0xffff0000u);
          int off0 = (col < 16) ? (64 + col * 16) : (448 + (col - 16) * 16);
          int off1 = (col + 1 < 16) ? (64 + (col + 1) * 16) : (448 + (col - 15) * 16);
          S[off0 + l16] = lo;
          S[off1 + l16] = hi;
        }
        if (lane < 16) {
          uint4 c4 = xr[4];
          unsigned wv4[4] = {c4.x, c4.y, c4.z, c4.w};
          #pragma unroll
          for (int p = 0; p < 4; ++p) {
            int col = 32 + 2 * p;
            S[448 + (col - 16) * 16 + lane] = __uint_as_float(wv4[p] << 16);
            S[448 + (col - 15) * 16 + lane] = __uint_as_float(wv4[p] & 0xffff0000u);
          }
        }
      } else {
        const float4* xr = reinterpret_cast<const float4*>(
            (const float*)x + (size_t)src * DIM);
        #pragma unroll
        for (int cc = 0; cc < 2; ++cc) {
          int c = quad + cc * 4;
          float4 t = xr[c];
          float vv[4] = {t.x, t.y, t.z, t.w};
          #pragma unroll
          for (int p = 0; p < 4; ++p) {
            int col = 4 * c + p;
            int offp = (col < 16) ? (64 + col * 16) : (448 + (col - 16) * 16);
            S[offp + l16] = vv[p];
          }
        }
        if (quad < 2) {
          int c = 8 + quad;
          float4 t = xr[c];
          float vv[4] = {t.x, t.y, t.z, t.w};
          #pragma unroll
          for (int p = 0; p < 4; ++p) {
            int col = 4 * c + p;
            S[448 + (col - 16) * 16 + l16] = vv[p];
          }
        }
      }
    }
    __builtin_amdgcn_wave_barrier();

    // ---- vds = (v . sh1) * inv_sqrt3 ----
    #pragma unroll
    for (int p = 0; p < 2; ++p) {
      int idx = lane + p * 64;
      int u = idx >> 4, e = idx & 15;
      float vdv = (S[448 + (u * 3 + 0) * 16 + e] * S[16 + e] +
                   S[448 + (u * 3 + 1) * 16 + e] * S[32 + e] +
                   S[448 + (u * 3 + 2) * 16 + e] * S[48 + e]) * C_INV_SQRT3;
      S[320 + u * 16 + e] = vdv;
    }
    __builtin_amdgcn_wave_barrier();

    // ---- h A-frag: lane holds h[edge=l16][k=quad*8+j] ----
    bf16x8_t af;
    {
      float eb[N_BASIS];
      if (BF16) {
        const unsigned short* er = (const unsigned short*)elemb + (size_t)(e0 + l16) * N_BASIS;
        #pragma unroll
        for (int p = 0; p < 5; ++p) {
          unsigned uv = *reinterpret_cast<const unsigned*>(er + p * 2);
          eb[2 * p]     = __uint_as_float(uv << 16);
          eb[2 * p + 1] = __uint_as_float(uv & 0xffff0000u);
        }
      } else {
        const float* er = (const float*)elemb + (size_t)(e0 + l16) * N_BASIS;
        #pragma unroll
        for (int p = 0; p < 5; ++p) {
          float2 fv = *reinterpret_cast<const float2*>(er + p * 2);
          eb[2 * p] = fv.x; eb[2 * p + 1] = fv.y;
        }
      }
      float hv[8];
      #pragma unroll
      for (int j = 0; j < 8; ++j) {
        int k = quad * 8 + j;
        float p = 0.f;
        #pragma unroll
        for (int b = 0; b < N_BASIS; ++b) p += eb[b] * w1s[b * MID + k];
        float z = p * C_INV_SQRT10;
        hv[j] = z / (1.f + __expf(-z)) * C_INV_SQRT32;
      }
      __align__(16) unsigned au[4];
      #pragma unroll
      for (int j = 0; j < 4; ++j) au[j] = pk2bf(hv[2 * j], hv[2 * j + 1]);
      af = *reinterpret_cast<const bf16x8_t*>(au);
    }

    f32x4_t s0 = *reinterpret_cast<const f32x4_t*>(&S[quad * 4]);  // sh0, 4 edges

    f32x4_t out0 = {0.f, 0.f, 0.f, 0.f};
    f32x4_t tsv  = {0.f, 0.f, 0.f, 0.f};
    f32x4_t tv0  = {0.f, 0.f, 0.f, 0.f};
    f32x4_t tv1  = {0.f, 0.f, 0.f, 0.f};
    f32x4_t tv2  = {0.f, 0.f, 0.f, 0.f};
    const f32x4_t zero = {0.f, 0.f, 0.f, 0.f};
    const int usel = (l16 >> 3);

    #pragma unroll
    for (int t = 0; t < 16; ++t) {   // ss0: u=t, k=l16 (B-frag from LDS broadcast)
      bf16x8_t bf = *reinterpret_cast<const bf16x8_t*>(&w2b[t * 512 + lane * 8]);
      f32x4_t D = mfma16x16x32(af, bf, zero);
      f32x4_t sv = *reinterpret_cast<const f32x4_t*>(&S[64 + t * 16 + quad * 4]);
      out0 += D * (sv * s0);
    }
    #pragma unroll
    for (int t = 0; t < 8; ++t) {    // vv0
      bf16x8_t bf = *reinterpret_cast<const bf16x8_t*>(&w2b[(16 + t) * 512 + lane * 8]);
      f32x4_t D = mfma16x16x32(af, bf, zero);
      f32x4_t vdv = *reinterpret_cast<const f32x4_t*>(&S[320 + t * 16 + quad * 4]);
      out0 += D * vdv;
    }
    #pragma unroll
    for (int t = 0; t < 8; ++t) {    // sv1: u=2t+usel, k=l16&7
      bf16x8_t bf = *reinterpret_cast<const bf16x8_t*>(&w2b[(24 + t) * 512 + lane * 8]);
      f32x4_t D = mfma16x16x32(af, bf, zero);
      int u = 2 * t + usel;
      f32x4_t sv = *reinterpret_cast<const f32x4_t*>(&S[64 + u * 16 + quad * 4]);
      tsv += D * sv;
    }
    #pragma unroll
    for (int t = 0; t < 4; ++t) {    // vs1: u=2t+usel, k=l16&7
      bf16x8_t bf = *reinterpret_cast<const bf16x8_t*>(&w2b[(32 + t) * 512 + lane * 8]);
      f32x4_t D = mfma16x16x32(af, bf, zero);
      int u = 2 * t + usel;
      f32x4_t v0 = *reinterpret_cast<const f32x4_t*>(&S[448 + (u * 3 + 0) * 16 + quad * 4]);
      f32x4_t v1 = *reinterpret_cast<const f32x4_t*>(&S[448 + (u * 3 + 1) * 16 + quad * 4]);
      f32x4_t v2 = *reinterpret_cast<const f32x4_t*>(&S[448 + (u * 3 + 2) * 16 + quad * 4]);
      tv0 += D * v0; tv1 += D * v1; tv2 += D * v2;
    }

    // combine u-parity halves (lanes l16 and l16^8)
    #pragma unroll
    for (int r = 0; r < 4; ++r) {
      tsv[r] += __shfl_xor(tsv[r], 8, 64);
      tv0[r] += __shfl_xor(tv0[r], 8, 64);
      tv1[r] += __shfl_xor(tv1[r], 8, 64);
      tv2[r] += __shfl_xor(tv2[r], 8, 64);
    }
    __builtin_amdgcn_wave_barrier();  // MFMA-loop S reads done; evs overlay begins

    // ---- epilogue into evs overlay (base +64, stride 42) ----
    #pragma unroll
    for (int r = 0; r < 4; ++r)
      S[64 + (quad * 4 + r) * 42 + l16] = C_A0C * out0[r];
    if (l16 < 8) {
      f32x4_t h1x = *reinterpret_cast<const f32x4_t*>(&S[16 + quad * 4]);
      f32x4_t h1y = *reinterpret_cast<const f32x4_t*>(&S[32 + quad * 4]);
      f32x4_t h1z = *reinterpret_cast<const f32x4_t*>(&S[48 + quad * 4]);
      #pragma unroll
      for (int r = 0; r < 4; ++r) {
        int rowb = 64 + (quad * 4 + r) * 42 + 16 + 3 * l16;
        S[rowb + 0] = C_A0C * (tsv[r] * h1x[r] + tv0[r] * s0[r]);
        S[rowb + 1] = C_A0C * (tsv[r] * h1y[r] + tv1[r] * s0[r]);
        S[rowb + 2] = C_A0C * (tsv[r] * h1z[r] + tv2[r] * s0[r]);
      }
    }
    __builtin_amdgcn_wave_barrier();

    // ---- scattered CSR-slot store: edge row -> ev[pos] (80B, 5x uint4) ----
    {
      const int edge = lane >> 2, chunk = lane & 3;     // chunks 0..3
      const float* rp = &S[64 + edge * 42 + chunk * 8];
      uint4 t;
      t.x = pk2bf(rp[0], rp[1]); t.y = pk2bf(rp[2], rp[3]);
      t.z = pk2bf(rp[4], rp[5]); t.w = pk2bf(rp[6], rp[7]);
      *reinterpret_cast<uint4*>(ev + (size_t)posA * DIM + chunk * 8) = t;
      if (lane < 16) {                                   // chunk 4 (cols 32..39)
        const float* rq = &S[64 + lane * 42 + 32];
        uint4 t2;
        t2.x = pk2bf(rq[0], rq[1]); t2.y = pk2bf(rq[2], rq[3]);
        t2.z = pk2bf(rq[4], rq[5]); t2.w = pk2bf(rq[6], rq[7]);
        *reinterpret_cast<uint4*>(ev + (size_t)posB * DIM + 32) = t2;
      }
    }
  }
}

__global__ __launch_bounds__(256, 3) void edge_mfma_kernel(
    const void* __restrict__ x,
    const void* __restrict__ edge_sh,
    const void* __restrict__ elemb,
    const void* __restrict__ W1,
    const void* __restrict__ W2,
    const void* __restrict__ gamma,    // dtype probe (all ones)
    const int* __restrict__ edge_src,
    const int* __restrict__ edge_dst,
    const int* __restrict__ rank,
    const int* __restrict__ off,
    const int* __restrict__ bbase,
    unsigned short* __restrict__ ev)
{
  __shared__ __align__(16) short w2b[36 * 512];   // 36,864 B
  __shared__ __align__(16) float w1s[N_BASIS * MID];
  __shared__ __align__(16) float stg[4 * 832];    // 13,312 B -> 51.5 KB, 3 blk/CU

  if (detect_bf16(gamma))
    edge_mfma_body<true >(x, edge_sh, elemb, W1, W2, edge_src, edge_dst, rank,
                          off, bbase, ev, w2b, w1s, stg);
  else
    edge_mfma_body<false>(x, edge_sh, elemb, W1, W2, edge_src, edge_dst, rank,
                          off, bbase, ev, w2b, w1s, stg);
}

// ---------------- phase 2: contiguous gather + LayerNorm (2 lanes/node) ----------------

template <bool BF16>
__device__ __forceinline__ void node_body(
    const unsigned short* __restrict__ ev,   // CSR-ordered rows
    const int* __restrict__ cnt,
    const int* __restrict__ off,             // block-partial offsets
    const int* __restrict__ bbase,           // scan block bases
    const void* __restrict__ gamma,
    const void* __restrict__ beta,
    const int* __restrict__ avg,
    void* __restrict__ out, int n, int half)
{
  const int c = cnt[n];
  const int o = off[n] + bbase[n >> 8];
  float s[20];
  #pragma unroll
  for (int d = 0; d < 20; ++d) s[d] = 0.f;

  // this half's 20 bf16 = 5 uint2 per row; row stride = 10 uint2
  const uint2* p = reinterpret_cast<const uint2*>(ev) + (size_t)o * 10 + half * 5;
  for (int j = 0; j < c; ++j) {
    #pragma unroll
    for (int q = 0; q < 5; ++q) {
      uint2 w = p[(size_t)j * 10 + q];
      s[q * 4 + 0] += __uint_as_float(w.x << 16);
      s[q * 4 + 1] += __uint_as_float(w.x & 0xffff0000u);
      s[q * 4 + 2] += __uint_as_float(w.y << 16);
      s[q * 4 + 3] += __uint_as_float(w.y & 0xffff0000u);
    }
  }

  const float inv = rsqrtf((float)avg[0]);
  float psum = 0.f;
  #pragma unroll
  for (int d = 0; d < 20; ++d) { s[d] *= inv; psum += s[d]; }
  const float mean = (psum + __shfl_xor(psum, 1, 64)) * (1.f / DIM);
  float pvar = 0.f;
  #pragma unroll
  for (int d = 0; d < 20; ++d) { float dd = s[d] - mean; pvar += dd * dd; }
  const float var = (pvar + __shfl_xor(pvar, 1, 64)) * (1.f / DIM);
  const float r = rsqrtf(var + 1e-5f);

  const int gb = half * 20;
  if (BF16) {
    #pragma unroll
    for (int d = 0; d < 20; ++d) {
      float y = (s[d] - mean) * r * ld<true>(gamma, gb + d) + ld<true>(beta, gb + d);
      ((unsigned short*)out)[(size_t)n * DIM + gb + d] = f2bf(y);
    }
  } else {
    float4* op = reinterpret_cast<float4*>((float*)out + (size_t)n * DIM + gb);
    #pragma unroll
    for (int q = 0; q < 5; ++q) {
      float4 t;
      t.x = (s[q*4+0] - mean) * r * ld<false>(gamma, gb+q*4+0) + ld<false>(beta, gb+q*4+0);
      t.y = (s[q*4+1] - mean) * r * ld<false>(gamma, gb+q*4+1) + ld<false>(beta, gb+q*4+1);
      t.z = (s[q*4+2] - mean) * r * ld<false>(gamma, gb+q*4+2) + ld<false>(beta, gb+q*4+2);
      t.w = (s[q*4+3] - mean) * r * ld<false>(gamma, gb+q*4+3) + ld<false>(beta, gb+q*4+3);
      op[q] = t;
    }
  }
}

__global__ __launch_bounds__(256) void node_kernel(
    const unsigned short* __restrict__ ev,
    const int* __restrict__ cnt,
    const int* __restrict__ off,
    const int* __restrict__ bbase,
    const void* __restrict__ gamma,
    const void* __restrict__ beta,
    const int* __restrict__ avg,
    void* __restrict__ out)
{
  const int t = blockIdx.x * blockDim.x + threadIdx.x;
  const int n = t >> 1;
  if (n >= N_NODES) return;
  const int half = t & 1;
  if (detect_bf16(gamma)) node_body<true >(ev, cnt, off, bbase, gamma, beta, avg, out, n, half);
  else                    node_body<false>(ev, cnt, off, bbase, gamma, beta, avg, out, n, half);
}

extern "C" void kernel_launch(void* const* d_in, const int* in_sizes, int n_in,
                              void* d_out, int out_size, void* d_ws, size_t ws_size,
                              hipStream_t stream) {
  const void* x       = d_in[0];
  const void* edge_sh = d_in[1];
  const void* elemb   = d_in[2];
  const void* W1      = d_in[3];
  const void* W2      = d_in[4];
  const void* gamma   = d_in[5];
  const void* beta    = d_in[6];
  const int* edge_src = (const int*)d_in[7];
  const int* edge_dst = (const int*)d_in[8];
  const int* avg      = (const int*)d_in[9];

  // workspace layout (42.4 MB)
  char* wsb = (char*)d_ws;
  unsigned short* ev = (unsigned short*)(wsb);            // 40,000,000 B (CSR order)
  int* rank  = (int*)(wsb + 40000000);                    //  2,000,000 B
  int* cnt   = (int*)(wsb + 42000000);                    //    200,000 B
  int* done  = (int*)(wsb + 42200000);                    //         64 B
  int* off   = (int*)(wsb + 42200064);                    //    200,000 B
  int* btot  = (int*)(wsb + 42400064);                    //        784 B
  int* bbase = (int*)(wsb + 42400912);                    //        784 B

  hipMemsetAsync(cnt, 0, 200064, stream);  // zero cnt + done

  const int EB = (N_EDGES + 255) / 256;    // 1954
  rank_kernel  <<<EB, 256, 0, stream>>>(edge_dst, cnt, rank);
  scanAB_kernel<<<SCAN_BLOCKS, 256, 0, stream>>>(cnt, off, btot, bbase, done);

  edge_mfma_kernel<<<768, 256, 0, stream>>>(x, edge_sh, elemb, W1, W2, gamma,
                                            edge_src, edge_dst, rank, off, bbase, ev);

  node_kernel<<<(2 * N_NODES + 255) / 256, 256, 0, stream>>>(
      ev, cnt, off, bbase, gamma, beta, avg, d_out);
}

// Round 13
// 216.672 us; speedup vs baseline: 1.0861x; 1.0735x over previous
//
#include <hip/hip_runtime.h>
#include <hip/hip_bf16.h>

#define N_NODES 50000
#define N_EDGES 500000
#define MUL0 16
#define MUL1 8
#define DIM 40            // MUL0 + 3*MUL1
#define N_BASIS 10
#define MID 32
#define WNUM 576          // 256 + 128 + 128 + 64
#define SCAN_BLOCKS 196   // ceil(50000/256)
#define N_GROUPS (N_EDGES / 16)   // 31250 exact

typedef __attribute__((ext_vector_type(8))) short bf16x8_t;
typedef __attribute__((ext_vector_type(4))) float f32x4_t;

__device__ __forceinline__ float bf2f(unsigned short u) {
  return __uint_as_float(((unsigned int)u) << 16);
}
__device__ __forceinline__ unsigned short f2bf(float f) {
  unsigned int x = __float_as_uint(f);
  unsigned int r = x + 0x7fffu + ((x >> 16) & 1u);  // RNE
  return (unsigned short)(r >> 16);
}
// packed f32x2 -> bf16x2 (v_cvt_pk_bf16_f32; RNE)
__device__ __forceinline__ unsigned pk2bf(float a, float b) {
  float2 f; f.x = a; f.y = b;
  __hip_bfloat162 h = __float22bfloat162_rn(f);
  return *reinterpret_cast<unsigned*>(&h);
}
// gamma is all-ones: bf16-packed pair -> 0x3F803F80 ; f32 -> 0x3F800000.
// Measured (r4/r5): live inputs are f32; bf16 branch kept as insurance.
__device__ __forceinline__ bool detect_bf16(const void* gamma) {
  return ((const unsigned int*)gamma)[0] == 0x3F803F80u;
}
template <bool BF16>
__device__ __forceinline__ float ld(const void* p, size_t i) {
  if (BF16) return bf2f(((const unsigned short*)p)[i]);
  return ((const float*)p)[i];
}

#define C_INV_SQRT10 0.31622776601683794f
#define C_INV_SQRT32 0.17677669529663687f
#define C_INV_SQRT3  0.5773502691896258f
#define C_A0C        0.20412414523193154f   // sqrt(1/24) == A0 == A1*INV_SQRT3

__device__ __forceinline__ f32x4_t mfma16x16x32(bf16x8_t a, bf16x8_t b, f32x4_t c) {
  return __builtin_amdgcn_mfma_f32_16x16x32_bf16(a, b, c, 0, 0, 0);
}

// ---------------- CSR build: ONE atomic pass, separate cheap scans ----------------
// r12 lesson: merged scanAB w/ per-block __threadfence costs ~25-30 us on gfx950
// (196 device-scope L2 drains) — two plain kernels are cheaper.
__global__ __launch_bounds__(256) void rank_kernel(
    const int* __restrict__ edge_dst, int* __restrict__ cnt,
    int* __restrict__ rank) {
  int e = blockIdx.x * 256 + threadIdx.x;
  if (e < N_EDGES) rank[e] = atomicAdd(&cnt[edge_dst[e]], 1);
}

__global__ __launch_bounds__(256) void scanA_kernel(
    const int* __restrict__ cnt, int* __restrict__ off, int* __restrict__ btot) {
  __shared__ int s[256];
  const int tid = threadIdx.x;
  const int i = blockIdx.x * 256 + tid;
  int v = (i < N_NODES) ? cnt[i] : 0;
  s[tid] = v;
  __syncthreads();
  for (int d = 1; d < 256; d <<= 1) {
    int t = (tid >= d) ? s[tid - d] : 0;
    __syncthreads();
    s[tid] += t;
    __syncthreads();
  }
  if (i < N_NODES) off[i] = s[tid] - v;            // block-local exclusive
  if (tid == 255) btot[blockIdx.x] = s[255];
}

__global__ __launch_bounds__(256) void scanB_kernel(
    const int* __restrict__ btot, int* __restrict__ bbase) {
  __shared__ int s[256];
  const int tid = threadIdx.x;
  int v = (tid < SCAN_BLOCKS) ? btot[tid] : 0;
  s[tid] = v;
  __syncthreads();
  for (int d = 1; d < 256; d <<= 1) {
    int t = (tid >= d) ? s[tid - d] : 0;
    __syncthreads();
    s[tid] += t;
    __syncthreads();
  }
  if (tid < SCAN_BLOCKS) bbase[tid] = s[tid] - v;  // exclusive block base
}

// ---------------- phase 1: MFMA edge kernel (r10 core; pos fused in) ----------------
// r9 lesson: no B-frag reg-cache (spills at (256,3) budget).
// r11 lesson: 512-thr/(512,4) forces 64-VGPR step -> spills. Stay at 256/(256,3).
// Per-wave staging S (floats, 832/wave):
//   +0   shs [4 comp][16 edge]
//   +64  sss [16 u][16 edge]
//   +320 vds [8 u][16 edge]
//   +448 vst [24 cc=u*3+i][16 edge]
//   evs overlays +64.. : [16 edge][42] (sss/vds/vst dead after MFMA loops)

template <bool BF16>
__device__ void edge_mfma_body(
    const void* __restrict__ x,
    const void* __restrict__ edge_sh,
    const void* __restrict__ elemb,
    const void* __restrict__ W1,
    const void* __restrict__ W2,
    const int* __restrict__ edge_src,
    const int* __restrict__ edge_dst,
    const int* __restrict__ rank,
    const int* __restrict__ off,
    const int* __restrict__ bbase,
    unsigned short* __restrict__ ev,
    short* __restrict__ w2b, float* __restrict__ w1s, float* __restrict__ stg)
{
  const int tid = threadIdx.x;

  // stage W2 into B-frag order: w2b[t*512+q*128+n*8+j] = bf16(W2[q*8+j][16t+n])
  for (int i = tid; i < 36 * 512; i += 256) {
    int m = i / WNUM;            // = q*8+j
    int col = i - m * WNUM;      // = t*16+n
    int q = m >> 3, j = m & 7;
    int t = col >> 4, n = col & 15;
    short val;
    if (BF16) val = (short)((const unsigned short*)W2)[i];
    else      val = (short)f2bf(((const float*)W2)[i]);
    w2b[t * 512 + q * 128 + n * 8 + j] = val;
  }
  for (int i = tid; i < N_BASIS * MID; i += 256) w1s[i] = ld<BF16>(W1, i);
  __syncthreads();

  const int lane = tid & 63;
  const int wid  = tid >> 6;
  const int quad = lane >> 4;
  const int l16  = lane & 15;
  float* S = stg + wid * 832;

  for (int gi = blockIdx.x * 4 + wid; gi < N_GROUPS; gi += gridDim.x * 4) {
    const int e0 = gi * 16;
    __builtin_amdgcn_wave_barrier();  // prev-iter evs reads vs this-iter staging writes

    // CSR slot computed in-kernel (posc fused): lane l holds pos of edge e0+l16
    const int eL   = e0 + l16;
    const int dL   = edge_dst[eL];
    const int posv = off[dL] + bbase[dL >> 8] + rank[eL];
    const int posA = __shfl(posv, lane >> 2, 64);   // edge lane>>2 (0..15)
    const int posB = posv;                           // used by lanes < 16

    // ---- stage edge_sh ----
    if (lane < 16) {
      if (BF16) {
        uint2 sw = *reinterpret_cast<const uint2*>(
            (const unsigned short*)edge_sh + (size_t)(e0 + lane) * 4);
        S[0 * 16 + lane] = __uint_as_float(sw.x << 16);
        S[1 * 16 + lane] = __uint_as_float(sw.x & 0xffff0000u);
        S[2 * 16 + lane] = __uint_as_float(sw.y << 16);
        S[3 * 16 + lane] = __uint_as_float(sw.y & 0xffff0000u);
      } else {
        float4 s4 = *reinterpret_cast<const float4*>(
            (const float*)edge_sh + (size_t)(e0 + lane) * 4);
        S[0 * 16 + lane] = s4.x; S[1 * 16 + lane] = s4.y;
        S[2 * 16 + lane] = s4.z; S[3 * 16 + lane] = s4.w;
      }
    }

    // ---- stage x[src]: col<16 -> sss, col>=16 -> vst ----
    {
      const int src = edge_src[e0 + l16];
      if (BF16) {
        const uint4* xr = reinterpret_cast<const uint4*>(
            (const unsigned short*)x + (size_t)src * DIM);
        uint4 c = xr[quad];
        unsigned wv[4] = {c.x, c.y, c.z, c.w};
        #pragma unroll
        for (int p = 0; p < 4; ++p) {
          int col = quad * 8 + 2 * p;
          float lo = __uint_as_float(wv[p] << 16);
          float hi = __uint_as_float(wv[p] & 0xffff0000u);
          int off0 = (col < 16) ? (64 + col * 16) : (448 + (col - 16) * 16);
          int off1 = (col + 1 < 16) ? (64 + (col + 1) * 16) : (448 + (col - 15) * 16);
          S[off0 + l16] = lo;
          S[off1 + l16] = hi;
        }
        if (lane < 16) {
          uint4 c4 = xr[4];
          unsigned wv4[4] = {c4.x, c4.y, c4.z, c4.w};
          #pragma unroll
          for (int p = 0; p < 4; ++p) {
            int col = 32 + 2 * p;
            S[448 + (col - 16) * 16 + lane] = __uint_as_float(wv4[p] << 16);
            S[448 + (col - 15) * 16 + lane] = __uint_as_float(wv4[p] & 0xffff0000u);
          }
        }
      } else {
        const float4* xr = reinterpret_cast<const float4*>(
            (const float*)x + (size_t)src * DIM);
        #pragma unroll
        for (int cc = 0; cc < 2; ++cc) {
          int c = quad + cc * 4;
          float4 t = xr[c];
          float vv[4] = {t.x, t.y, t.z, t.w};
          #pragma unroll
          for (int p = 0; p < 4; ++p) {
            int col = 4 * c + p;
            int offp = (col < 16) ? (64 + col * 16) : (448 + (col - 16) * 16);
            S[offp + l16] = vv[p];
          }
        }
        if (quad < 2) {
          int c = 8 + quad;
          float4 t = xr[c];
          float vv[4] = {t.x, t.y, t.z, t.w};
          #pragma unroll
          for (int p = 0; p < 4; ++p) {
            int col = 4 * c + p;
            S[448 + (col - 16) * 16 + l16] = vv[p];
          }
        }
      }
    }
    __builtin_amdgcn_wave_barrier();

    // ---- vds = (v . sh1) * inv_sqrt3 ----
    #pragma unroll
    for (int p = 0; p < 2; ++p) {
      int idx = lane + p * 64;
      int u = idx >> 4, e = idx & 15;
      float vdv = (S[448 + (u * 3 + 0) * 16 + e] * S[16 + e] +
                   S[448 + (u * 3 + 1) * 16 + e] * S[32 + e] +
                   S[448 + (u * 3 + 2) * 16 + e] * S[48 + e]) * C_INV_SQRT3;
      S[320 + u * 16 + e] = vdv;
    }
    __builtin_amdgcn_wave_barrier();

    // ---- h A-frag: lane holds h[edge=l16][k=quad*8+j] ----
    bf16x8_t af;
    {
      float eb[N_BASIS];
      if (BF16) {
        const unsigned short* er = (const unsigned short*)elemb + (size_t)(e0 + l16) * N_BASIS;
        #pragma unroll
        for (int p = 0; p < 5; ++p) {
          unsigned uv = *reinterpret_cast<const unsigned*>(er + p * 2);
          eb[2 * p]     = __uint_as_float(uv << 16);
          eb[2 * p + 1] = __uint_as_float(uv & 0xffff0000u);
        }
      } else {
        const float* er = (const float*)elemb + (size_t)(e0 + l16) * N_BASIS;
        #pragma unroll
        for (int p = 0; p < 5; ++p) {
          float2 fv = *reinterpret_cast<const float2*>(er + p * 2);
          eb[2 * p] = fv.x; eb[2 * p + 1] = fv.y;
        }
      }
      float hv[8];
      #pragma unroll
      for (int j = 0; j < 8; ++j) {
        int k = quad * 8 + j;
        float p = 0.f;
        #pragma unroll
        for (int b = 0; b < N_BASIS; ++b) p += eb[b] * w1s[b * MID + k];
        float z = p * C_INV_SQRT10;
        hv[j] = z / (1.f + __expf(-z)) * C_INV_SQRT32;
      }
      __align__(16) unsigned au[4];
      #pragma unroll
      for (int j = 0; j < 4; ++j) au[j] = pk2bf(hv[2 * j], hv[2 * j + 1]);
      af = *reinterpret_cast<const bf16x8_t*>(au);
    }

    f32x4_t s0 = *reinterpret_cast<const f32x4_t*>(&S[quad * 4]);  // sh0, 4 edges

    f32x4_t out0 = {0.f, 0.f, 0.f, 0.f};
    f32x4_t tsv  = {0.f, 0.f, 0.f, 0.f};
    f32x4_t tv0  = {0.f, 0.f, 0.f, 0.f};
    f32x4_t tv1  = {0.f, 0.f, 0.f, 0.f};
    f32x4_t tv2  = {0.f, 0.f, 0.f, 0.f};
    const f32x4_t zero = {0.f, 0.f, 0.f, 0.f};
    const int usel = (l16 >> 3);

    #pragma unroll
    for (int t = 0; t < 16; ++t) {   // ss0: u=t, k=l16 (B-frag from LDS broadcast)
      bf16x8_t bf = *reinterpret_cast<const bf16x8_t*>(&w2b[t * 512 + lane * 8]);
      f32x4_t D = mfma16x16x32(af, bf, zero);
      f32x4_t sv = *reinterpret_cast<const f32x4_t*>(&S[64 + t * 16 + quad * 4]);
      out0 += D * (sv * s0);
    }
    #pragma unroll
    for (int t = 0; t < 8; ++t) {    // vv0
      bf16x8_t bf = *reinterpret_cast<const bf16x8_t*>(&w2b[(16 + t) * 512 + lane * 8]);
      f32x4_t D = mfma16x16x32(af, bf, zero);
      f32x4_t vdv = *reinterpret_cast<const f32x4_t*>(&S[320 + t * 16 + quad * 4]);
      out0 += D * vdv;
    }
    #pragma unroll
    for (int t = 0; t < 8; ++t) {    // sv1: u=2t+usel, k=l16&7
      bf16x8_t bf = *reinterpret_cast<const bf16x8_t*>(&w2b[(24 + t) * 512 + lane * 8]);
      f32x4_t D = mfma16x16x32(af, bf, zero);
      int u = 2 * t + usel;
      f32x4_t sv = *reinterpret_cast<const f32x4_t*>(&S[64 + u * 16 + quad * 4]);
      tsv += D * sv;
    }
    #pragma unroll
    for (int t = 0; t < 4; ++t) {    // vs1: u=2t+usel, k=l16&7
      bf16x8_t bf = *reinterpret_cast<const bf16x8_t*>(&w2b[(32 + t) * 512 + lane * 8]);
      f32x4_t D = mfma16x16x32(af, bf, zero);
      int u = 2 * t + usel;
      f32x4_t v0 = *reinterpret_cast<const f32x4_t*>(&S[448 + (u * 3 + 0) * 16 + quad * 4]);
      f32x4_t v1 = *reinterpret_cast<const f32x4_t*>(&S[448 + (u * 3 + 1) * 16 + quad * 4]);
      f32x4_t v2 = *reinterpret_cast<const f32x4_t*>(&S[448 + (u * 3 + 2) * 16 + quad * 4]);
      tv0 += D * v0; tv1 += D * v1; tv2 += D * v2;
    }

    // combine u-parity halves (lanes l16 and l16^8)
    #pragma unroll
    for (int r = 0; r < 4; ++r) {
      tsv[r] += __shfl_xor(tsv[r], 8, 64);
      tv0[r] += __shfl_xor(tv0[r], 8, 64);
      tv1[r] += __shfl_xor(tv1[r], 8, 64);
      tv2[r] += __shfl_xor(tv2[r], 8, 64);
    }
    __builtin_amdgcn_wave_barrier();  // MFMA-loop S reads done; evs overlay begins

    // ---- epilogue into evs overlay (base +64, stride 42) ----
    #pragma unroll
    for (int r = 0; r < 4; ++r)
      S[64 + (quad * 4 + r) * 42 + l16] = C_A0C * out0[r];
    if (l16 < 8) {
      f32x4_t h1x = *reinterpret_cast<const f32x4_t*>(&S[16 + quad * 4]);
      f32x4_t h1y = *reinterpret_cast<const f32x4_t*>(&S[32 + quad * 4]);
      f32x4_t h1z = *reinterpret_cast<const f32x4_t*>(&S[48 + quad * 4]);
      #pragma unroll
      for (int r = 0; r < 4; ++r) {
        int rowb = 64 + (quad * 4 + r) * 42 + 16 + 3 * l16;
        S[rowb + 0] = C_A0C * (tsv[r] * h1x[r] + tv0[r] * s0[r]);
        S[rowb + 1] = C_A0C * (tsv[r] * h1y[r] + tv1[r] * s0[r]);
        S[rowb + 2] = C_A0C * (tsv[r] * h1z[r] + tv2[r] * s0[r]);
      }
    }
    __builtin_amdgcn_wave_barrier();

    // ---- scattered CSR-slot store: edge row -> ev[pos] (80B, 5x uint4) ----
    {
      const int edge = lane >> 2, chunk = lane & 3;     // chunks 0..3
      const float* rp = &S[64 + edge * 42 + chunk * 8];
      uint4 t;
      t.x = pk2bf(rp[0], rp[1]); t.y = pk2bf(rp[2], rp[3]);
      t.z = pk2bf(rp[4], rp[5]); t.w = pk2bf(rp[6], rp[7]);
      *reinterpret_cast<uint4*>(ev + (size_t)posA * DIM + chunk * 8) = t;
      if (lane < 16) {                                   // chunk 4 (cols 32..39)
        const float* rq = &S[64 + lane * 42 + 32];
        uint4 t2;
        t2.x = pk2bf(rq[0], rq[1]); t2.y = pk2bf(rq[2], rq[3]);
        t2.z = pk2bf(rq[4], rq[5]); t2.w = pk2bf(rq[6], rq[7]);
        *reinterpret_cast<uint4*>(ev + (size_t)posB * DIM + 32) = t2;
      }
    }
  }
}

__global__ __launch_bounds__(256, 3) void edge_mfma_kernel(
    const void* __restrict__ x,
    const void* __restrict__ edge_sh,
    const void* __restrict__ elemb,
    const void* __restrict__ W1,
    const void* __restrict__ W2,
    const void* __restrict__ gamma,    // dtype probe (all ones)
    const int* __restrict__ edge_src,
    const int* __restrict__ edge_dst,
    const int* __restrict__ rank,
    const int* __restrict__ off,
    const int* __restrict__ bbase,
    unsigned short* __restrict__ ev)
{
  __shared__ __align__(16) short w2b[36 * 512];   // 36,864 B
  __shared__ __align__(16) float w1s[N_BASIS * MID];
  __shared__ __align__(16) float stg[4 * 832];    // 13,312 B -> 51.5 KB, 3 blk/CU

  if (detect_bf16(gamma))
    edge_mfma_body<true >(x, edge_sh, elemb, W1, W2, edge_src, edge_dst, rank,
                          off, bbase, ev, w2b, w1s, stg);
  else
    edge_mfma_body<false>(x, edge_sh, elemb, W1, W2, edge_src, edge_dst, rank,
                          off, bbase, ev, w2b, w1s, stg);
}

// ---------------- phase 2: contiguous gather + LayerNorm (2 lanes/node) ----------------

template <bool BF16>
__device__ __forceinline__ void node_body(
    const unsigned short* __restrict__ ev,   // CSR-ordered rows
    const int* __restrict__ cnt,
    const int* __restrict__ off,             // block-partial offsets
    const int* __restrict__ bbase,           // scan block bases
    const void* __restrict__ gamma,
    const void* __restrict__ beta,
    const int* __restrict__ avg,
    void* __restrict__ out, int n, int half)
{
  const int c = cnt[n];
  const int o = off[n] + bbase[n >> 8];
  float s[20];
  #pragma unroll
  for (int d = 0; d < 20; ++d) s[d] = 0.f;

  // this half's 20 bf16 = 5 uint2 per row; row stride = 10 uint2
  const uint2* p = reinterpret_cast<const uint2*>(ev) + (size_t)o * 10 + half * 5;
  for (int j = 0; j < c; ++j) {
    #pragma unroll
    for (int q = 0; q < 5; ++q) {
      uint2 w = p[(size_t)j * 10 + q];
      s[q * 4 + 0] += __uint_as_float(w.x << 16);
      s[q * 4 + 1] += __uint_as_float(w.x & 0xffff0000u);
      s[q * 4 + 2] += __uint_as_float(w.y << 16);
      s[q * 4 + 3] += __uint_as_float(w.y & 0xffff0000u);
    }
  }

  const float inv = rsqrtf((float)avg[0]);
  float psum = 0.f;
  #pragma unroll
  for (int d = 0; d < 20; ++d) { s[d] *= inv; psum += s[d]; }
  const float mean = (psum + __shfl_xor(psum, 1, 64)) * (1.f / DIM);
  float pvar = 0.f;
  #pragma unroll
  for (int d = 0; d < 20; ++d) { float dd = s[d] - mean; pvar += dd * dd; }
  const float var = (pvar + __shfl_xor(pvar, 1, 64)) * (1.f / DIM);
  const float r = rsqrtf(var + 1e-5f);

  const int gb = half * 20;
  if (BF16) {
    #pragma unroll
    for (int d = 0; d < 20; ++d) {
      float y = (s[d] - mean) * r * ld<true>(gamma, gb + d) + ld<true>(beta, gb + d);
      ((unsigned short*)out)[(size_t)n * DIM + gb + d] = f2bf(y);
    }
  } else {
    float4* op = reinterpret_cast<float4*>((float*)out + (size_t)n * DIM + gb);
    #pragma unroll
    for (int q = 0; q < 5; ++q) {
      float4 t;
      t.x = (s[q*4+0] - mean) * r * ld<false>(gamma, gb+q*4+0) + ld<false>(beta, gb+q*4+0);
      t.y = (s[q*4+1] - mean) * r * ld<false>(gamma, gb+q*4+1) + ld<false>(beta, gb+q*4+1);
      t.z = (s[q*4+2] - mean) * r * ld<false>(gamma, gb+q*4+2) + ld<false>(beta, gb+q*4+2);
      t.w = (s[q*4+3] - mean) * r * ld<false>(gamma, gb+q*4+3) + ld<false>(beta, gb+q*4+3);
      op[q] = t;
    }
  }
}

__global__ __launch_bounds__(256) void node_kernel(
    const unsigned short* __restrict__ ev,
    const int* __restrict__ cnt,
    const int* __restrict__ off,
    const int* __restrict__ bbase,
    const void* __restrict__ gamma,
    const void* __restrict__ beta,
    const int* __restrict__ avg,
    void* __restrict__ out)
{
  const int t = blockIdx.x * blockDim.x + threadIdx.x;
  const int n = t >> 1;
  if (n >= N_NODES) return;
  const int half = t & 1;
  if (detect_bf16(gamma)) node_body<true >(ev, cnt, off, bbase, gamma, beta, avg, out, n, half);
  else                    node_body<false>(ev, cnt, off, bbase, gamma, beta, avg, out, n, half);
}

extern "C" void kernel_launch(void* const* d_in, const int* in_sizes, int n_in,
                              void* d_out, int out_size, void* d_ws, size_t ws_size,
                              hipStream_t stream) {
  const void* x       = d_in[0];
  const void* edge_sh = d_in[1];
  const void* elemb   = d_in[2];
  const void* W1      = d_in[3];
  const void* W2      = d_in[4];
  const void* gamma   = d_in[5];
  const void* beta    = d_in[6];
  const int* edge_src = (const int*)d_in[7];
  const int* edge_dst = (const int*)d_in[8];
  const int* avg      = (const int*)d_in[9];

  // workspace layout (42.4 MB)
  char* wsb = (char*)d_ws;
  unsigned short* ev = (unsigned short*)(wsb);            // 40,000,000 B (CSR order)
  int* rank  = (int*)(wsb + 40000000);                    //  2,000,000 B
  int* cnt   = (int*)(wsb + 42000000);                    //    200,000 B
  int* off   = (int*)(wsb + 42200000);                    //    200,000 B
  int* btot  = (int*)(wsb + 42400000);                    //        784 B
  int* bbase = (int*)(wsb + 42400800);                    //        784 B

  hipMemsetAsync(cnt, 0, 200000, stream);  // zero counts only

  const int EB = (N_EDGES + 255) / 256;    // 1954
  rank_kernel <<<EB, 256, 0, stream>>>(edge_dst, cnt, rank);
  scanA_kernel<<<SCAN_BLOCKS, 256, 0, stream>>>(cnt, off, btot);
  scanB_kernel<<<1, 256, 0, stream>>>(btot, bbase);

  edge_mfma_kernel<<<768, 256, 0, stream>>>(x, edge_sh, elemb, W1, W2, gamma,
                                            edge_src, edge_dst, rank, off, bbase, ev);

  node_kernel<<<(2 * N_NODES + 255) / 256, 256, 0, stream>>>(
      ev, cnt, off, bbase, gamma, beta, avg, d_out);
}